// Round 8
// baseline (355.813 us; speedup 1.0000x reference)
//
#include <hip/hip_runtime.h>

#define N_ROWS 1024
#define M_COLS 16384
#define DIM 512

constexpr float GAMMA_ = 0.1f;
constexpr float INV_GAMMA = 10.0f;
constexpr float EPS_ = 0.005f;
constexpr float TINY_ = 1e-30f;
constexpr float RVAL = 1.0f / 1024.0f;
constexpr float CVAL = 1.0f / 16384.0f;

typedef __attribute__((ext_vector_type(8))) short bf16x8;
typedef __attribute__((ext_vector_type(4))) float f32x4;

__device__ __forceinline__ float waveRedSum(float v) {
#pragma unroll
    for (int o = 32; o > 0; o >>= 1) v += __shfl_down(v, o);
    return v;
}

// ---- L2-bypassing (coherent-point) accesses: relaxed system-scope atomics ----
__device__ __forceinline__ unsigned sysloadu(const unsigned* p) {
    return __hip_atomic_load(p, __ATOMIC_RELAXED, __HIP_MEMORY_SCOPE_SYSTEM);
}
__device__ __forceinline__ void sysstoreu(unsigned* p, unsigned v) {
    __hip_atomic_store(p, v, __ATOMIC_RELAXED, __HIP_MEMORY_SCOPE_SYSTEM);
}
__device__ __forceinline__ float sysloadf(const float* p) {
    return __hip_atomic_load(p, __ATOMIC_RELAXED, __HIP_MEMORY_SCOPE_SYSTEM);
}
__device__ __forceinline__ void sysstoref(float* p, float v) {
    __hip_atomic_store(p, v, __ATOMIC_RELAXED, __HIP_MEMORY_SCOPE_SYSTEM);
}

// ---- bf16 split helper (RNE) ----
__device__ __forceinline__ unsigned bf16b(float f) {
    unsigned u = __float_as_uint(f);
    return (u + 0x7FFFu + ((u >> 16) & 1u)) >> 16;
}

// ---- 2-hop reduce-broadcast tree (8 groups x 32 writers), data-carrying ----
// Caller has already sc-stored its per-row partials into
// spart2[p][g][row][w32] (+ err row 1024 if used). Returns the fully
// reduced value for row==tid. Leaders are blocks 0..7 (group g==b).
template<bool MINOP>
__device__ __forceinline__ float tree_exchange(float* __restrict__ spart2,
        float* __restrict__ sxcd, unsigned* __restrict__ warr,
        unsigned* __restrict__ xcdrep, const int b, const int tid,
        const int p, const unsigned ep, const bool doErr) {
    const int g = b & 7, w32 = b >> 3;
    __syncthreads();   // drains vmcnt: all waves' partial sc-stores acked at L3
    if (tid == 0) sysstoreu(&warr[(g << 5) + w32], ep);
    if (b < 8) {
        if (tid < 32) {
            while (sysloadu(&warr[(b << 5) + tid]) < ep) __builtin_amdgcn_s_sleep(1);
        }
        __syncthreads();
        {
            const float* sp = spart2 + ((size_t)((p << 3) + b) * 1056 + tid) * 32;
            float tv[32];
#pragma unroll
            for (int i = 0; i < 32; ++i) tv[i] = sysloadf(&sp[i]);
            float v0 = tv[0];
#pragma unroll
            for (int i = 1; i < 32; ++i) v0 = MINOP ? fminf(v0, tv[i]) : (v0 + tv[i]);
            sysstoref(&sxcd[((size_t)p * 1025 + tid) * 8 + b], v0);
            if (!MINOP && doErr && tid == 0) {
                const float* epr = spart2 + ((size_t)((p << 3) + b) * 1056 + 1024) * 32;
                float ev[32];
#pragma unroll
                for (int i = 0; i < 32; ++i) ev[i] = sysloadf(&epr[i]);
                float es = ev[0];
#pragma unroll
                for (int i = 1; i < 32; ++i) es += ev[i];
                sysstoref(&sxcd[((size_t)p * 1025 + 1024) * 8 + b], es);
            }
        }
        __syncthreads();   // drain leader stores
        if (tid < 32) sysstoreu(&xcdrep[(b << 5) + tid], ep);
    }
    if (tid < 8) {
        while (sysloadu(&xcdrep[(tid << 5) + w32]) < ep) __builtin_amdgcn_s_sleep(1);
    }
    __syncthreads();
    const float* sr = sxcd + ((size_t)p * 1025 + tid) * 8;
    float rv[8];
#pragma unroll
    for (int i = 0; i < 8; ++i) rv[i] = sysloadf(&sr[i]);
    float r = rv[0];
#pragma unroll
    for (int i = 1; i < 8; ++i) r = MINOP ? fminf(r, rv[i]) : (r + rv[i]);
    return r;
}

// ---- conv_x: f32 -> bf16 hi/lo (linear layout) + row sqnorm. 1024 blk x 64 thr ----
__global__ void conv_x(const float* __restrict__ X, unsigned short* __restrict__ xh,
                       unsigned short* __restrict__ xl, float* __restrict__ sx) {
    const int row = blockIdx.x, t = threadIdx.x;
    const float* xr = X + (size_t)row * DIM + t * 8;
    float4 a = *(const float4*)xr, c = *(const float4*)(xr + 4);
    float v[8] = {a.x, a.y, a.z, a.w, c.x, c.y, c.z, c.w};
    unsigned hs[8], ls[8];
    float sq = 0.f;
#pragma unroll
    for (int j = 0; j < 8; ++j) {
        unsigned h = bf16b(v[j]);
        hs[j] = h;
        ls[j] = bf16b(v[j] - __uint_as_float(h << 16));
        sq = fmaf(v[j], v[j], sq);
    }
    uint4 hv = make_uint4(hs[0] | (hs[1] << 16), hs[2] | (hs[3] << 16),
                          hs[4] | (hs[5] << 16), hs[6] | (hs[7] << 16));
    uint4 lv = make_uint4(ls[0] | (ls[1] << 16), ls[2] | (ls[3] << 16),
                          ls[4] | (ls[5] << 16), ls[6] | (ls[7] << 16));
    const size_t off = (size_t)row * 1024 + t * 16;   // bytes
    *(uint4*)((char*)xh + off) = hv;
    *(uint4*)((char*)xl + off) = lv;
    sq = waveRedSum(sq);
    if (t == 0) sx[row] = sq;
}

// ---- conv_y: same but PRE-SWIZZLED (byte ^ ((row&7)<<4)) per 1KB row ----
__global__ void conv_y(const float* __restrict__ Y, unsigned short* __restrict__ yh,
                       unsigned short* __restrict__ yl, float* __restrict__ sy) {
    const int row = blockIdx.x, t = threadIdx.x;
    const float* yr = Y + (size_t)row * DIM + t * 8;
    float4 a = *(const float4*)yr, c = *(const float4*)(yr + 4);
    float v[8] = {a.x, a.y, a.z, a.w, c.x, c.y, c.z, c.w};
    unsigned hs[8], ls[8];
    float sq = 0.f;
#pragma unroll
    for (int j = 0; j < 8; ++j) {
        unsigned h = bf16b(v[j]);
        hs[j] = h;
        ls[j] = bf16b(v[j] - __uint_as_float(h << 16));
        sq = fmaf(v[j], v[j], sq);
    }
    uint4 hv = make_uint4(hs[0] | (hs[1] << 16), hs[2] | (hs[3] << 16),
                          hs[4] | (hs[5] << 16), hs[6] | (hs[7] << 16));
    uint4 lv = make_uint4(ls[0] | (ls[1] << 16), ls[2] | (ls[3] << 16),
                          ls[4] | (ls[5] << 16), ls[6] | (ls[7] << 16));
    const size_t off = ((size_t)row * 1024 + t * 16) ^ ((size_t)((row & 7) << 4));
    *(uint4*)((char*)yh + off) = hv;
    *(uint4*)((char*)yl + off) = lv;
    sq = waveRedSum(sq);
    if (t == 0) sy[row] = sq;
}

// ---- per-launch state init (graph replays do NOT re-poison ws/out) ----
__global__ void init_state(unsigned* __restrict__ flags, float* __restrict__ out) {
    int idx = blockIdx.x * blockDim.x + threadIdx.x;
    if (idx < 512) flags[idx] = 0u;
    if (idx == 0) out[0] = 0.0f;
}

// ---- FUSED: split-bf16 MFMA gemm -> M frags -> tree row-min -> K=exp ->
// Sinkhorn with ONE tree-exchange per iteration -> P/loss epilogue.
// 256 blocks x 1024 thr. Block b owns cols [64b,64b+64), wave w rows [64w,64w+64).
// kf[i][j][reg]: row = 64w+16i+4q+reg (q=lane>>4), col(local) = 16j+l15.
__global__ __launch_bounds__(1024) void sinkhorn_full(
        const unsigned short* __restrict__ xh, const unsigned short* __restrict__ xl,
        const unsigned short* __restrict__ yh, const unsigned short* __restrict__ yl,
        const float* __restrict__ sx, const float* __restrict__ sy,
        float* __restrict__ sxcd, unsigned* __restrict__ flags,
        float* __restrict__ out) {
    const int tid = threadIdx.x;
    const int b = blockIdx.x;
    const int lane = tid & 63;
    const int w = tid >> 6;
    const int l15 = lane & 15;
    const int q = lane >> 4;
    const int g = b & 7, w32 = b >> 3;
    float* Pbuf = out + 1;
    float* spart2 = out + 10000000;          // [2][8][1056][32] f32 (dead P region)
    unsigned* warr = flags;                  // [256]
    unsigned* xcdrep = flags + 256;          // [256]

    __shared__ __align__(16) char ldsY[131072];
    __shared__ float sx_lds[1024];
    __shared__ float mmin_lds[1024];
    __shared__ float u_lds[2][1024];
    __shared__ float sy_lds[64];
    __shared__ float v_lds[2][64];
    __shared__ float t_acc[16][68];
    __shared__ float red[16];
    __shared__ float sh_err;
    __shared__ float sh_eprev;

    // ---- stage y tile (swizzle-preserving linear copy) + small state ----
    {
        const char* ysrcH = (const char*)yh + (size_t)b * 65536;
        const char* ysrcL = (const char*)yl + (size_t)b * 65536;
#pragma unroll
        for (int p = 0; p < 4; ++p) {
            const int d = tid * 16 + p * 16384;
            *(uint4*)(ldsY + d) = *(const uint4*)(ysrcH + d);
            *(uint4*)(ldsY + 65536 + d) = *(const uint4*)(ysrcL + d);
        }
        sx_lds[tid] = sx[tid];
        u_lds[0][tid] = 1.0f;
        u_lds[1][tid] = 1.0f;
        if (tid < 64) {
            sy_lds[tid] = sy[(b << 6) + tid];
            v_lds[0][tid] = 1.0f;
            v_lds[1][tid] = 1.0f;
        }
        if (tid == 0) { sh_eprev = 0.0f; }
    }
    __syncthreads();

    // ---- gemm: kf = x . y^T (3-pass split bf16) ----
    f32x4 kf[4][4] = {};
    {
        const int rowbase = (w << 6) + l15;
        const int kofs = q * 8;
#pragma unroll 1
        for (int ks = 0; ks < 16; ++ks) {
            bf16x8 ah[4], al[4], bh[4], bl[4];
#pragma unroll
            for (int i = 0; i < 4; ++i) {
                const size_t xo = (size_t)(rowbase + i * 16) * 512 + ks * 32 + kofs;
                ah[i] = *(const bf16x8*)(xh + xo);
                al[i] = *(const bf16x8*)(xl + xo);
                const int cl = i * 16 + l15;
                const int bo = (cl * 1024 + ks * 64 + q * 16) ^ ((cl & 7) << 4);
                bh[i] = *(const bf16x8*)(ldsY + bo);
                bl[i] = *(const bf16x8*)(ldsY + 65536 + bo);
            }
#pragma unroll
            for (int i = 0; i < 4; ++i)
#pragma unroll
                for (int j = 0; j < 4; ++j) {
                    kf[i][j] = __builtin_amdgcn_mfma_f32_16x16x32_bf16(ah[i], bh[j], kf[i][j], 0, 0, 0);
                    kf[i][j] = __builtin_amdgcn_mfma_f32_16x16x32_bf16(ah[i], bl[j], kf[i][j], 0, 0, 0);
                    kf[i][j] = __builtin_amdgcn_mfma_f32_16x16x32_bf16(al[i], bh[j], kf[i][j], 0, 0, 0);
                }
        }
    }
    // ---- kf := M; publish per-block row-min partials; tree-min ----
#pragma unroll
    for (int i = 0; i < 4; ++i)
#pragma unroll
        for (int j = 0; j < 4; ++j) {
            const float syv = sy_lds[j * 16 + l15];
#pragma unroll
            for (int reg = 0; reg < 4; ++reg) {
                const int r = (w << 6) + i * 16 + (q << 2) + reg;
                kf[i][j][reg] = sx_lds[r] + syv - 2.0f * kf[i][j][reg];
            }
        }
    {
        float mn[4][4];
#pragma unroll
        for (int i = 0; i < 4; ++i)
#pragma unroll
            for (int reg = 0; reg < 4; ++reg) {
                float m = fminf(fminf(kf[i][0][reg], kf[i][1][reg]),
                                fminf(kf[i][2][reg], kf[i][3][reg]));
#pragma unroll
                for (int o = 1; o < 16; o <<= 1) m = fminf(m, __shfl_xor(m, o));
                mn[i][reg] = m;
            }
        if (l15 == 0) {
#pragma unroll
            for (int i = 0; i < 4; ++i)
#pragma unroll
                for (int reg = 0; reg < 4; ++reg) {
                    const int r = (w << 6) + i * 16 + (q << 2) + reg;
                    sysstoref(&spart2[((size_t)g * 1056 + r) * 32 + w32], mn[i][reg]);
                }
        }
    }
    mmin_lds[tid] = tree_exchange<true>(spart2, sxcd, warr, xcdrep, b, tid, 0, 1u, false);
    __syncthreads();
    // ---- K = exp(-gamma*(M - Mmin)) in frags ----
#pragma unroll
    for (int i = 0; i < 4; ++i)
#pragma unroll
        for (int j = 0; j < 4; ++j)
#pragma unroll
            for (int reg = 0; reg < 4; ++reg) {
                const int r = (w << 6) + i * 16 + (q << 2) + reg;
                kf[i][j][reg] = __expf(-GAMMA_ * (kf[i][j][reg] - mmin_lds[r]));
            }

    // ---- Sinkhorn loop: ONE tree exchange per iteration ----
    int cur = 0, vsel = 0, brk = 0;
    int it = 0;
    for (;; ++it) {
        const int p = it & 1;
        const unsigned ep = (unsigned)it + 2u;
        // pass 1: row-partials of s over this block's 64 cols
        {
            float vv[4];
#pragma unroll
            for (int j = 0; j < 4; ++j) vv[j] = v_lds[cur][j * 16 + l15];
            float rs[4][4];
#pragma unroll
            for (int i = 0; i < 4; ++i)
#pragma unroll
                for (int reg = 0; reg < 4; ++reg) {
                    float pp = kf[i][0][reg] * vv[0];
                    pp = fmaf(kf[i][1][reg], vv[1], pp);
                    pp = fmaf(kf[i][2][reg], vv[2], pp);
                    pp = fmaf(kf[i][3][reg], vv[3], pp);
#pragma unroll
                    for (int o = 1; o < 16; o <<= 1) pp += __shfl_xor(pp, o);
                    rs[i][reg] = pp;
                }
            if (l15 == 0) {
#pragma unroll
                for (int i = 0; i < 4; ++i)
#pragma unroll
                    for (int reg = 0; reg < 4; ++reg) {
                        const int r = (w << 6) + i * 16 + (q << 2) + reg;
                        sysstoref(&spart2[((size_t)((p << 3) + g) * 1056 + r) * 32 + w32], rs[i][reg]);
                    }
            }
            if (tid == 0)
                sysstoref(&spart2[((size_t)((p << 3) + g) * 1056 + 1024) * 32 + w32], sh_eprev);
        }
        // exchange: s (row tid) fully reduced; err travels as row 1024
        float srow = tree_exchange<false>(spart2, sxcd, warr, xcdrep, b, tid, p, ep, true);
        // u update (redundant, deterministic, identical in all blocks)
        {
            float uo = u_lds[p ^ 1][tid];
            u_lds[p][tid] = uo * RVAL / fmaxf(uo * srow, TINY_);   // speculative at break
        }
        if (tid == 0) {
            float e = 0.f;
            if (it > 0) {
                const float* er = sxcd + ((size_t)p * 1025 + 1024) * 8;
                float ev[8];
#pragma unroll
                for (int i = 0; i < 8; ++i) ev[i] = sysloadf(&er[i]);
#pragma unroll
                for (int i = 0; i < 8; ++i) e += ev[i];
            }
            sh_err = (it > 0) ? e : 1e30f;
        }
        __syncthreads();
        float err = sh_err;
        brk = (err <= EPS_) ? 1 : ((it == 1000) ? 2 : 0);
        if (brk) { vsel = (brk == 1) ? (cur ^ 1) : cur; break; }
        // pass 2: t for own 64 cols; v update; err partial (published next iter)
        {
            float uu[4][4];
#pragma unroll
            for (int i = 0; i < 4; ++i)
#pragma unroll
                for (int reg = 0; reg < 4; ++reg)
                    uu[i][reg] = u_lds[p][(w << 6) + i * 16 + (q << 2) + reg];
            float tj[4];
#pragma unroll
            for (int j = 0; j < 4; ++j) {
                float t = 0.f;
#pragma unroll
                for (int i = 0; i < 4; ++i)
#pragma unroll
                    for (int reg = 0; reg < 4; ++reg)
                        t = fmaf(kf[i][j][reg], uu[i][reg], t);
                t += __shfl_xor(t, 16);
                t += __shfl_xor(t, 32);
                tj[j] = t;
            }
            if (q == 0) {
#pragma unroll
                for (int j = 0; j < 4; ++j) t_acc[w][j * 16 + l15] = tj[j];
            }
        }
        __syncthreads();
        if (tid < 64) {
            float t = 0.f;
#pragma unroll
            for (int w2 = 0; w2 < 16; ++w2) t += t_acc[w2][tid];
            float vc = v_lds[cur][tid];
            float beta = vc * t;
            float e = fabsf(beta - CVAL);
            v_lds[cur ^ 1][tid] = vc * CVAL / fmaxf(beta, TINY_);
            e = waveRedSum(e);
            if (tid == 0) sh_eprev = e;
        }
        __syncthreads();
        cur ^= 1;
    }

    // ---- epilogue: P = u K v; loss = sum P*(Mmin - ln(K)/gamma) ----
    const int usel = (it & 1) ^ 1;
    float vv[4];
#pragma unroll
    for (int j = 0; j < 4; ++j) vv[j] = v_lds[vsel][j * 16 + l15];
    float lsum = 0.f;
#pragma unroll
    for (int i = 0; i < 4; ++i)
#pragma unroll
        for (int reg = 0; reg < 4; ++reg) {
            const int r = (w << 6) + i * 16 + (q << 2) + reg;
            const float ur = u_lds[usel][r];
            const float mmr = mmin_lds[r];
            float* prow = Pbuf + (size_t)r * M_COLS + (b << 6) + l15;
#pragma unroll
            for (int j = 0; j < 4; ++j) {
                float kv = kf[i][j][reg];
                float pv = 0.f;
                if (kv > 0.f) {
                    pv = ur * kv * vv[j];
                    lsum = fmaf(pv, mmr - __logf(kv) * INV_GAMMA, lsum);
                }
                prow[j * 16] = pv;
            }
        }
    lsum = waveRedSum(lsum);
    if (lane == 0) red[w] = lsum;
    __syncthreads();
    if (tid == 0) {
        float s = 0.f;
#pragma unroll
        for (int i2 = 0; i2 < 16; ++i2) s += red[i2];
        atomicAdd(out, s);
    }
}

extern "C" void kernel_launch(void* const* d_in, const int* in_sizes, int n_in,
                              void* d_out, int out_size, void* d_ws, size_t ws_size,
                              hipStream_t stream) {
    const float* x = (const float*)d_in[0];
    const float* y = (const float*)d_in[1];
    float* out = (float*)d_out;
    float* ws = (float*)d_ws;
    float* sx   = ws;                            // 1024
    float* sy   = ws + 1024;                     // 16384
    float* sxcd = ws + 18432;                    // 2 x 1025 x 8 = 16400 f32
    unsigned* flags = (unsigned*)(ws + 36864);   // 512 uints

    // scratch in the dead P-region of d_out (all consumed before P write):
    unsigned short* xh = (unsigned short*)(out + 300000);    // 1024x512 bf16
    unsigned short* xl = (unsigned short*)(out + 600000);
    unsigned short* yh = (unsigned short*)(out + 900000);    // 16384x512 (pre-swizzled)
    unsigned short* yl = (unsigned short*)(out + 5200000);
    // spart2 at out + 10000000 (addressed inside the kernel)

    conv_x<<<N_ROWS, 64, 0, stream>>>(x, xh, xl, sx);
    conv_y<<<M_COLS, 64, 0, stream>>>(y, yh, yl, sy);
    init_state<<<2, 256, 0, stream>>>(flags, out);
    {
        const unsigned short *xhc = xh, *xlc = xl, *yhc = yh, *ylc = yl;
        const float *sxc = sx, *syc = sy;
        void* args[] = {(void*)&xhc, (void*)&xlc, (void*)&yhc, (void*)&ylc,
                        (void*)&sxc, (void*)&syc, (void*)&sxcd, (void*)&flags,
                        (void*)&out};
        hipLaunchCooperativeKernel((const void*)sinkhorn_full, dim3(256), dim3(1024), args, 0, stream);
    }
}

// Round 9
// 209.008 us; speedup vs baseline: 1.7024x; 1.7024x over previous
//
#include <hip/hip_runtime.h>

#define N_ROWS 1024
#define M_COLS 16384
#define DIM 512

constexpr float GAMMA_ = 0.1f;
constexpr float INV_GAMMA = 10.0f;
constexpr float EPS_ = 0.005f;
constexpr float TINY_ = 1e-30f;
constexpr float RVAL = 1.0f / 1024.0f;
constexpr float CVAL = 1.0f / 16384.0f;

typedef __attribute__((ext_vector_type(8))) short bf16x8;
typedef __attribute__((ext_vector_type(4))) float f32x4;

__device__ __forceinline__ float waveRedSum(float v) {
#pragma unroll
    for (int o = 32; o > 0; o >>= 1) v += __shfl_down(v, o);
    return v;
}
__device__ __forceinline__ float waveRedMin(float v) {
#pragma unroll
    for (int o = 32; o > 0; o >>= 1) v = fminf(v, __shfl_down(v, o));
    return v;
}

// ---- L2-bypassing (coherent-point) accesses: relaxed system-scope atomics ----
__device__ __forceinline__ unsigned sysloadu(const unsigned* p) {
    return __hip_atomic_load(p, __ATOMIC_RELAXED, __HIP_MEMORY_SCOPE_SYSTEM);
}
__device__ __forceinline__ void sysstoreu(unsigned* p, unsigned v) {
    __hip_atomic_store(p, v, __ATOMIC_RELAXED, __HIP_MEMORY_SCOPE_SYSTEM);
}
__device__ __forceinline__ float sysloadf(const float* p) {
    return __hip_atomic_load(p, __ATOMIC_RELAXED, __HIP_MEMORY_SCOPE_SYSTEM);
}
__device__ __forceinline__ void sysstoref(float* p, float v) {
    __hip_atomic_store(p, v, __ATOMIC_RELAXED, __HIP_MEMORY_SCOPE_SYSTEM);
}

// ---- fence-free barrier, R5 topology (block0 sweeps, broadcasts): ~0.95us ----
__device__ __forceinline__ void gbarx(unsigned* __restrict__ arr, unsigned* __restrict__ bcast,
                                      int b, int tid, unsigned e) {
    __syncthreads();                       // drains vmcnt: all waves' sys-stores acked at L3
    if (tid == 0) sysstoreu(&arr[b], e);
    if (b == 0) {
        if (tid < 256) {
            while (sysloadu(&arr[tid]) < e) __builtin_amdgcn_s_sleep(1);
        }
        __syncthreads();
        if (tid == 0) sysstoreu(bcast, e);
    } else {
        if (tid == 0) {
            while (sysloadu(bcast) < e) __builtin_amdgcn_s_sleep(1);
        }
    }
    __syncthreads();
}

// ---- bf16 split helper (RNE) ----
__device__ __forceinline__ unsigned bf16b(float f) {
    unsigned u = __float_as_uint(f);
    return (u + 0x7FFFu + ((u >> 16) & 1u)) >> 16;
}

// ---- conv_x: f32 -> bf16 hi/lo (linear layout) + row sqnorm. 1024 blk x 64 thr ----
__global__ void conv_x(const float* __restrict__ X, unsigned short* __restrict__ xh,
                       unsigned short* __restrict__ xl, float* __restrict__ sx) {
    const int row = blockIdx.x, t = threadIdx.x;
    const float* xr = X + (size_t)row * DIM + t * 8;
    float4 a = *(const float4*)xr, c = *(const float4*)(xr + 4);
    float v[8] = {a.x, a.y, a.z, a.w, c.x, c.y, c.z, c.w};
    unsigned hs[8], ls[8];
    float sq = 0.f;
#pragma unroll
    for (int j = 0; j < 8; ++j) {
        unsigned h = bf16b(v[j]);
        hs[j] = h;
        ls[j] = bf16b(v[j] - __uint_as_float(h << 16));
        sq = fmaf(v[j], v[j], sq);
    }
    uint4 hv = make_uint4(hs[0] | (hs[1] << 16), hs[2] | (hs[3] << 16),
                          hs[4] | (hs[5] << 16), hs[6] | (hs[7] << 16));
    uint4 lv = make_uint4(ls[0] | (ls[1] << 16), ls[2] | (ls[3] << 16),
                          ls[4] | (ls[5] << 16), ls[6] | (ls[7] << 16));
    const size_t off = (size_t)row * 1024 + t * 16;   // bytes
    *(uint4*)((char*)xh + off) = hv;
    *(uint4*)((char*)xl + off) = lv;
    sq = waveRedSum(sq);
    if (t == 0) sx[row] = sq;
}

// ---- per-launch state init (graph replays do NOT re-poison ws/out) ----
__global__ void init_state(float* __restrict__ ubuf, unsigned* __restrict__ flags,
                           float* __restrict__ out) {
    int idx = blockIdx.x * blockDim.x + threadIdx.x;
    if (idx < 512) flags[idx] = 0u;
    if (idx < 512) { ubuf[idx * 4] = 1.0f; ubuf[idx * 4 + 1] = 1.0f;
                     ubuf[idx * 4 + 2] = 1.0f; ubuf[idx * 4 + 3] = 1.0f; }
    if (idx == 0) out[0] = 0.0f;
}

// ---- FUSED: y-tile f32->split-bf16 staging + MFMA gemm (K in C-fragments) +
// row-min exchange + K=exp + Sinkhorn (2 gbarx/iter) + P/loss epilogue.
// 256 blocks x 1024 thr. Block b owns cols [64b,64b+64), wave w rows [64w,64w+64).
// kf[i][j][reg]: row = 64w+16i+4q+reg (q=lane>>4), col(local) = 16j+l15.
// spart2 layout: [writer b][1056] (rows 0..1023 + err slot 1024), publish is one
// coalesced 256B sc-store per wave via LDS redistribute.
__global__ __launch_bounds__(1024, 4) void sinkhorn_full(
        const unsigned short* __restrict__ xh, const unsigned short* __restrict__ xl,
        const float* __restrict__ Y, const float* __restrict__ sx,
        float* __restrict__ ubuf, float* __restrict__ Mming,
        float* __restrict__ out, unsigned* __restrict__ flags) {
    const int tid = threadIdx.x;
    const int b = blockIdx.x;
    const int lane = tid & 63;
    const int w = tid >> 6;
    const int l15 = lane & 15;
    const int q = lane >> 4;
    float* Pbuf = out + 1;
    float* spart2 = out + 10000000;          // [256][1056] f32 (dead P region)
    unsigned* arr = flags;                   // [256]
    unsigned* bcast = flags + 288;           // separate line

    __shared__ __align__(16) char ldsY[131072];   // hi 64KB | lo 64KB, swizzled
    __shared__ float sx_lds[1024];
    __shared__ float mmin_lds[1024];
    __shared__ float u_lds[1024];
    __shared__ float sy_lds[64];
    __shared__ float v_lds[2][64];
    __shared__ float t_acc[16][68];
    __shared__ float srow_lds[16][64];
    __shared__ float red[16];
    __shared__ float sh_err;
    __shared__ float sh_eprev;

    // ---- stage y tile: f32 -> split bf16 -> swizzled LDS; sy partials ----
    {
        const int row = tid >> 4;       // 0..63 (block's local col index)
        const int c = tid & 15;         // 32 f32 chunk within the row
        const float* yr = Y + (size_t)((b << 6) + row) * DIM + c * 32;
        const int swz = (row & 7) << 4;
        float sq = 0.f;
#pragma unroll
        for (int s2 = 0; s2 < 4; ++s2) {
            float4 f0 = *(const float4*)(yr + s2 * 8);
            float4 f1 = *(const float4*)(yr + s2 * 8 + 4);
            float v8[8] = {f0.x, f0.y, f0.z, f0.w, f1.x, f1.y, f1.z, f1.w};
            unsigned h[8], lo[8];
#pragma unroll
            for (int j = 0; j < 8; ++j) {
                h[j] = bf16b(v8[j]);
                lo[j] = bf16b(v8[j] - __uint_as_float(h[j] << 16));
                sq = fmaf(v8[j], v8[j], sq);
            }
            const int off = (row * 1024 + c * 64 + s2 * 16) ^ swz;
            *(uint4*)(ldsY + off) = make_uint4(h[0] | (h[1] << 16), h[2] | (h[3] << 16),
                                               h[4] | (h[5] << 16), h[6] | (h[7] << 16));
            *(uint4*)(ldsY + 65536 + off) = make_uint4(lo[0] | (lo[1] << 16), lo[2] | (lo[3] << 16),
                                                       lo[4] | (lo[5] << 16), lo[6] | (lo[7] << 16));
        }
        float* sy_part = (float*)t_acc;     // [64][17] = 1088 floats, fits t_acc exactly
        sy_part[row * 17 + c] = sq;
        sx_lds[tid] = sx[tid];
        if (tid < 64) { v_lds[0][tid] = 1.0f; v_lds[1][tid] = 1.0f; }
        if (tid == 0) sh_eprev = 0.0f;
    }
    __syncthreads();
    if (tid < 64) {
        const float* sy_part = (const float*)t_acc;
        float s = 0.f;
#pragma unroll
        for (int c2 = 0; c2 < 16; ++c2) s += sy_part[tid * 17 + c2];
        sy_lds[tid] = s;
    }
    __syncthreads();

    // ---- gemm: kf = x . y^T (3-pass split bf16) ----
    f32x4 kf[4][4] = {};
    {
        const int rowbase = (w << 6) + l15;
        const int kofs = q * 8;
#pragma unroll 1
        for (int ks = 0; ks < 16; ++ks) {
            bf16x8 ah[4], al[4], bh[4], bl[4];
#pragma unroll
            for (int i = 0; i < 4; ++i) {
                const size_t xo = (size_t)(rowbase + i * 16) * 512 + ks * 32 + kofs;
                ah[i] = *(const bf16x8*)(xh + xo);
                al[i] = *(const bf16x8*)(xl + xo);
                const int cl = i * 16 + l15;
                const int bo = (cl * 1024 + ks * 64 + q * 16) ^ ((cl & 7) << 4);
                bh[i] = *(const bf16x8*)(ldsY + bo);
                bl[i] = *(const bf16x8*)(ldsY + 65536 + bo);
            }
#pragma unroll
            for (int i = 0; i < 4; ++i)
#pragma unroll
                for (int j = 0; j < 4; ++j) {
                    kf[i][j] = __builtin_amdgcn_mfma_f32_16x16x32_bf16(ah[i], bh[j], kf[i][j], 0, 0, 0);
                    kf[i][j] = __builtin_amdgcn_mfma_f32_16x16x32_bf16(ah[i], bl[j], kf[i][j], 0, 0, 0);
                    kf[i][j] = __builtin_amdgcn_mfma_f32_16x16x32_bf16(al[i], bh[j], kf[i][j], 0, 0, 0);
                }
        }
    }
    // ---- kf := M = sx + sy - 2*dot ----
#pragma unroll
    for (int i = 0; i < 4; ++i)
#pragma unroll
        for (int j = 0; j < 4; ++j) {
            const float syv = sy_lds[j * 16 + l15];
#pragma unroll
            for (int reg = 0; reg < 4; ++reg) {
                const int r = (w << 6) + i * 16 + (q << 2) + reg;
                kf[i][j][reg] = sx_lds[r] + syv - 2.0f * kf[i][j][reg];
            }
        }
    // ---- row-min partials: xor-reduce (all lanes valid) -> LDS redistribute ->
    // one coalesced 256B publish per wave ----
    {
        float mn[4][4];
#pragma unroll
        for (int i = 0; i < 4; ++i)
#pragma unroll
            for (int reg = 0; reg < 4; ++reg) {
                float m = fminf(fminf(kf[i][0][reg], kf[i][1][reg]),
                                fminf(kf[i][2][reg], kf[i][3][reg]));
#pragma unroll
                for (int o = 1; o < 16; o <<= 1) m = fminf(m, __shfl_xor(m, o));
                mn[i][reg] = m;
            }
        if (l15 == 0) {
#pragma unroll
            for (int i = 0; i < 4; ++i)
#pragma unroll
                for (int reg = 0; reg < 4; ++reg)
                    srow_lds[w][i * 16 + (q << 2) + reg] = mn[i][reg];
        }
        __syncthreads();
        sysstoref(&spart2[(size_t)b * 1056 + (w << 6) + lane], srow_lds[w][lane]);
    }
    gbarx(arr, bcast, b, tid, 1u);
    // owner block b reduces rows 4b..4b+3 over 256 writers (waves 1..4)
    if (w >= 1 && w <= 4) {
        const int r = (b << 2) + (w - 1);
        float m = fminf(fminf(sysloadf(&spart2[(size_t)lane * 1056 + r]),
                              sysloadf(&spart2[(size_t)(lane + 64) * 1056 + r])),
                        fminf(sysloadf(&spart2[(size_t)(lane + 128) * 1056 + r]),
                              sysloadf(&spart2[(size_t)(lane + 192) * 1056 + r])));
        m = waveRedMin(m);
        if (lane == 0) sysstoref(&Mming[r], m);
    }
    gbarx(arr, bcast, b, tid, 2u);
    if (tid < 256) {
#pragma unroll
        for (int k2 = 0; k2 < 4; ++k2) mmin_lds[tid * 4 + k2] = sysloadf(&Mming[tid * 4 + k2]);
    }
    __syncthreads();
    // ---- K = exp(-gamma*(M - Mmin)) in frags ----
#pragma unroll
    for (int i = 0; i < 4; ++i)
#pragma unroll
        for (int j = 0; j < 4; ++j)
#pragma unroll
            for (int reg = 0; reg < 4; ++reg) {
                const int r = (w << 6) + i * 16 + (q << 2) + reg;
                kf[i][j][reg] = __expf(-GAMMA_ * (kf[i][j][reg] - mmin_lds[r]));
            }

    // ---- Sinkhorn loop (R7 semantics; coalesced publish; 2 gbarx/iter) ----
    int cur = 0, vsel = 0, brk = 0;
    int it = 0;
    for (;; ++it) {
        const unsigned ep = 3u + 2u * (unsigned)it;
        // pass 1: row-partials of s over this block's 64 cols
        {
            float vv[4];
#pragma unroll
            for (int j = 0; j < 4; ++j) vv[j] = v_lds[cur][j * 16 + l15];
            float rs[4][4];
#pragma unroll
            for (int i = 0; i < 4; ++i)
#pragma unroll
                for (int reg = 0; reg < 4; ++reg) {
                    float pp = kf[i][0][reg] * vv[0];
                    pp = fmaf(kf[i][1][reg], vv[1], pp);
                    pp = fmaf(kf[i][2][reg], vv[2], pp);
                    pp = fmaf(kf[i][3][reg], vv[3], pp);
#pragma unroll
                    for (int o = 1; o < 16; o <<= 1) pp += __shfl_xor(pp, o);
                    rs[i][reg] = pp;
                }
            if (l15 == 0) {
#pragma unroll
                for (int i = 0; i < 4; ++i)
#pragma unroll
                    for (int reg = 0; reg < 4; ++reg)
                        srow_lds[w][i * 16 + (q << 2) + reg] = rs[i][reg];
            }
            __syncthreads();
            sysstoref(&spart2[(size_t)b * 1056 + (w << 6) + lane], srow_lds[w][lane]);
            if (tid == 0) sysstoref(&spart2[(size_t)b * 1056 + 1024], sh_eprev);
        }
        gbarx(arr, bcast, b, tid, ep);   // barrier A: spart + prev errpart visible
        float* uOld = ubuf + (((it & 1) ^ 1) << 10);
        float* uNew = ubuf + ((it & 1) << 10);
        {
            if (w == 0) {
                float e = 0.f;
                if (it > 0)
                    e = sysloadf(&spart2[(size_t)lane * 1056 + 1024]) +
                        sysloadf(&spart2[(size_t)(lane + 64) * 1056 + 1024]) +
                        sysloadf(&spart2[(size_t)(lane + 128) * 1056 + 1024]) +
                        sysloadf(&spart2[(size_t)(lane + 192) * 1056 + 1024]);
                e = waveRedSum(e);
                if (lane == 0) sh_err = (it > 0) ? e : 1e30f;
            } else if (w <= 4) {
                const int r = (b << 2) + (w - 1);
                float s = sysloadf(&spart2[(size_t)lane * 1056 + r]) +
                          sysloadf(&spart2[(size_t)(lane + 64) * 1056 + r]) +
                          sysloadf(&spart2[(size_t)(lane + 128) * 1056 + r]) +
                          sysloadf(&spart2[(size_t)(lane + 192) * 1056 + r]);
                s = waveRedSum(s);
                if (lane == 0) {
                    float uo = sysloadf(&uOld[r]);
                    sysstoref(&uNew[r], uo * RVAL / fmaxf(uo * s, TINY_));  // speculative at break
                }
            }
        }
        __syncthreads();
        float err = sh_err;
        brk = (err <= EPS_) ? 1 : ((it == 1000) ? 2 : 0);
        gbarx(arr, bcast, b, tid, ep + 1u);  // barrier B: u visible / epilogue-safety
        if (brk) { vsel = (brk == 1) ? (cur ^ 1) : cur; break; }
        if (tid < 256) {
#pragma unroll
            for (int k2 = 0; k2 < 4; ++k2) u_lds[tid * 4 + k2] = sysloadf(&uNew[tid * 4 + k2]);
        }
        __syncthreads();
        // pass 2: t for own 64 cols; v update; err partial (published next iter)
        {
            float uu[4][4];
#pragma unroll
            for (int i = 0; i < 4; ++i)
#pragma unroll
                for (int reg = 0; reg < 4; ++reg)
                    uu[i][reg] = u_lds[(w << 6) + i * 16 + (q << 2) + reg];
            float tj[4];
#pragma unroll
            for (int j = 0; j < 4; ++j) {
                float t = 0.f;
#pragma unroll
                for (int i = 0; i < 4; ++i)
#pragma unroll
                    for (int reg = 0; reg < 4; ++reg)
                        t = fmaf(kf[i][j][reg], uu[i][reg], t);
                t += __shfl_xor(t, 16);
                t += __shfl_xor(t, 32);
                tj[j] = t;
            }
            if (q == 0) {
#pragma unroll
                for (int j = 0; j < 4; ++j) t_acc[w][j * 16 + l15] = tj[j];
            }
        }
        __syncthreads();
        if (tid < 64) {
            float t = 0.f;
#pragma unroll
            for (int w2 = 0; w2 < 16; ++w2) t += t_acc[w2][tid];
            float vc = v_lds[cur][tid];
            float beta = vc * t;
            float e = fabsf(beta - CVAL);
            v_lds[cur ^ 1][tid] = vc * CVAL / fmaxf(beta, TINY_);
            e = waveRedSum(e);
            if (tid == 0) sh_eprev = e;
        }
        __syncthreads();
        cur ^= 1;
    }

    // ---- epilogue: P = u K v; loss = sum P*(Mmin - ln(K)/gamma) ----
    const float* uEpi = ubuf + (((it & 1) ^ 1) << 10);
    if (tid < 256) {
#pragma unroll
        for (int k2 = 0; k2 < 4; ++k2) u_lds[tid * 4 + k2] = sysloadf(&uEpi[tid * 4 + k2]);
    }
    __syncthreads();
    float vv[4];
#pragma unroll
    for (int j = 0; j < 4; ++j) vv[j] = v_lds[vsel][j * 16 + l15];
    float lsum = 0.f;
#pragma unroll
    for (int i = 0; i < 4; ++i)
#pragma unroll
        for (int reg = 0; reg < 4; ++reg) {
            const int r = (w << 6) + i * 16 + (q << 2) + reg;
            const float ur = u_lds[r];
            const float mmr = mmin_lds[r];
            float* prow = Pbuf + (size_t)r * M_COLS + (b << 6) + l15;
#pragma unroll
            for (int j = 0; j < 4; ++j) {
                float kv = kf[i][j][reg];
                float pv = 0.f;
                if (kv > 0.f) {
                    pv = ur * kv * vv[j];
                    lsum = fmaf(pv, mmr - __logf(kv) * INV_GAMMA, lsum);
                }
                prow[j * 16] = pv;
            }
        }
    lsum = waveRedSum(lsum);
    if (lane == 0) red[w] = lsum;
    __syncthreads();
    if (tid == 0) {
        float s = 0.f;
#pragma unroll
        for (int i2 = 0; i2 < 16; ++i2) s += red[i2];
        atomicAdd(out, s);
    }
}

extern "C" void kernel_launch(void* const* d_in, const int* in_sizes, int n_in,
                              void* d_out, int out_size, void* d_ws, size_t ws_size,
                              hipStream_t stream) {
    const float* x = (const float*)d_in[0];
    const float* y = (const float*)d_in[1];
    float* out = (float*)d_out;
    float* ws = (float*)d_ws;
    float* sx    = ws;                           // 1024
    float* Mming = ws + 1024;                    // 1024
    float* ubuf  = ws + 2048;                    // 2 x 1024
    unsigned* flags = (unsigned*)(ws + 4096);    // 512 uints

    // scratch in the dead P-region of d_out (all consumed before P write):
    unsigned short* xh = (unsigned short*)(out + 300000);    // 1024x512 bf16
    unsigned short* xl = (unsigned short*)(out + 600000);
    // spart2 at out + 10000000 (addressed inside the kernel)

    conv_x<<<N_ROWS, 64, 0, stream>>>(x, xh, xl, sx);
    init_state<<<2, 256, 0, stream>>>(ubuf, flags, out);
    {
        const unsigned short *xhc = xh, *xlc = xl;
        const float *yc = y, *sxc = sx;
        void* args[] = {(void*)&xhc, (void*)&xlc, (void*)&yc, (void*)&sxc,
                        (void*)&ubuf, (void*)&Mming, (void*)&out, (void*)&flags};
        hipLaunchCooperativeKernel((const void*)sinkhorn_full, dim3(256), dim3(1024), args, 0, stream);
    }
}